// Round 4
// baseline (52549.060 us; speedup 1.0000x reference)
//
#include <hip/hip_runtime.h>
#include <stdint.h>

// SNN LIF multi-layer, B=16384, D_IN=N=512, L=3, T=32 (T hardcoded).
//
// Round 4: the recurrent GEMM must reproduce the reference's f32 FMA-chain
// REALIZATION bit-exactly (round 3 proved even a correctly-rounded exact dot
// flips spikes). So: f32 vector FMA, single accumulator per output, k
// ascending 0..511 — round 1's semantics — but restructured to be VALU-bound
// instead of LDS-bound:
//   - lane = batch row; 32-col accumulator stripe per lane
//   - weights (WtT[k][n], pre-transposed, L2-resident) via wave-uniform
//     scalar loads -> SGPR operand of v_fmac  => NO LDS traffic for B
//   - A (spikes bf16 {0,1} / x f32) staged in LDS transposed [k][m]:
//     ONE ds_read_b32 per lane per k  => 32 fma per LDS float (was 4)
//   - epilogue does LIF math per-lane, routed through a per-wave LDS
//     transpose so all global u/x1/a/s accesses stay coalesced
// Round-1-verbatim state math (PASSed with absmax 0.0).

#define B_SZ 16384
#define N_SZ 512
#define K_SZ 512
#define T_STEPS 32
#define LEAKY 0.9f

#define BM 64            // batch rows per block
#define BN 128           // cols per block (4 waves * 32)
#define TNW 32           // cols per lane
#define BK 32            // k chunk
#define NCHUNK (K_SZ / BK)
#define TRS 17           // transpose buffer stride (floats)

union U32F { uint32_t u; float f; };
__device__ inline float bf16f(uint16_t h){ U32F v; v.u = ((uint32_t)h) << 16; return v.f; }

// AMODE: 0 = none, 1 = a := s, 2 = a := a*LEAKY + s
template<bool A_BF16, int AMODE, bool ADD_U, bool ADD_X1, bool STORE_C>
__global__ __launch_bounds__(256, 4)
void vgemm_lif(const void* __restrict__ Aptr,    // [B][512] bf16 spikes or f32 x
               const float* __restrict__ WtT,    // [512 k][512 n] f32 (= W.T)
               const float* __restrict__ bias,   // [512]
               const float* u_prev,              // may alias u_out
               const float* __restrict__ x1,
               float* u_out,
               uint16_t* __restrict__ s_out,     // [B][512] bf16 bits
               float* a_ptr,
               float* __restrict__ c_out)        // x1 store (pre-LIF)
{
    __shared__ float As[2][BK][BM];       // 16 KB, [k][m] transposed
    __shared__ float Tr[4][BM][TRS];      // 17.4 KB, per-wave epilogue transpose

    const int tid = threadIdx.x;
    const int l   = tid & 63;
    const int w   = __builtin_amdgcn_readfirstlane(tid >> 6);
    const int m0  = blockIdx.y * BM;
    const int n0w = blockIdx.x * BN + w * TNW;

    // staging coords: 32 rows x 8 col-groups (x2 row-halves)
    const int rs = tid >> 3;   // 0..31
    const int cs = tid & 7;    // 0..7

    float acc[TNW];
    #pragma unroll
    for (int j = 0; j < TNW; ++j) acc[j] = 0.f;

    // ---------- staging helpers ----------
    ushort4 preU[2];
    float4  preF[2];
    auto stage_load = [&](int c) {
        const int k0 = c * BK;
        #pragma unroll
        for (int h = 0; h < 2; ++h) {
            const size_t off = (size_t)(m0 + h * 32 + rs) * K_SZ + k0 + cs * 4;
            if (A_BF16) preU[h] = *(const ushort4*)((const uint16_t*)Aptr + off);
            else        preF[h] = *(const float4*)((const float*)Aptr + off);
        }
    };
    auto stage_write = [&](int buf) {
        #pragma unroll
        for (int h = 0; h < 2; ++h) {
            const int m = h * 32 + rs;
            if (A_BF16) {
                As[buf][cs*4+0][m] = bf16f(preU[h].x);
                As[buf][cs*4+1][m] = bf16f(preU[h].y);
                As[buf][cs*4+2][m] = bf16f(preU[h].z);
                As[buf][cs*4+3][m] = bf16f(preU[h].w);
            } else {
                As[buf][cs*4+0][m] = preF[h].x;
                As[buf][cs*4+1][m] = preF[h].y;
                As[buf][cs*4+2][m] = preF[h].z;
                As[buf][cs*4+3][m] = preF[h].w;
            }
        }
    };

    // ---------- main loop: k ascending, single acc per output ----------
    stage_load(0);
    stage_write(0);
    __syncthreads();

    int buf = 0;
    for (int c = 0; c < NCHUNK; ++c) {
        if (c + 1 < NCHUNK) stage_load(c + 1);

        const int k0 = c * BK;
        #pragma unroll
        for (int kk = 0; kk < BK; ++kk) {
            // weights: wave-uniform address -> scalar loads -> SGPR operand
            const float* wr = WtT + (size_t)(k0 + kk) * N_SZ + n0w;
            const float av = As[buf][kk][l];
            #pragma unroll
            for (int j4 = 0; j4 < 8; ++j4) {
                const float4 wv = ((const float4*)wr)[j4];
                acc[j4*4+0] = fmaf(av, wv.x, acc[j4*4+0]);
                acc[j4*4+1] = fmaf(av, wv.y, acc[j4*4+1]);
                acc[j4*4+2] = fmaf(av, wv.z, acc[j4*4+2]);
                acc[j4*4+3] = fmaf(av, wv.w, acc[j4*4+3]);
            }
        }

        if (c + 1 < NCHUNK) stage_write(buf ^ 1);
        __syncthreads();
        buf ^= 1;
    }

    // ---------- epilogue: per-wave transpose -> coalesced global ops ----------
    const int jcol = l & 15;
    const int hrow = l >> 4;       // 0..3
    #pragma unroll
    for (int q = 0; q < 2; ++q) {
        #pragma unroll
        for (int jj = 0; jj < 16; ++jj)
            Tr[w][l][jj] = acc[q * 16 + jj];
        // (same-wave ds ordering; compiler inserts lgkmcnt)
        const int col = n0w + q * 16 + jcol;
        const float bv = bias[col];
        #pragma unroll 4
        for (int p = 0; p < 16; ++p) {
            const int rml = p * 4 + hrow;
            const size_t idx = (size_t)(m0 + rml) * N_SZ + col;
            float v = Tr[w][rml][jcol] + bv;     // (mm + b)
            if (ADD_U)  v += u_prev[idx];        // + u
            if (ADD_X1) v += x1[idx];            // + x1
            if (STORE_C) c_out[idx] = v;
            const float sv = (v >= 1.0f) ? 1.0f : 0.0f;
            u_out[idx] = (v - 2.0f * sv) * LEAKY;
            s_out[idx] = (v >= 1.0f) ? (uint16_t)0x3F80 : (uint16_t)0;
            if (AMODE == 1)      a_ptr[idx] = sv;
            else if (AMODE == 2) a_ptr[idx] = a_ptr[idx] * LEAKY + sv;
        }
        __builtin_amdgcn_s_waitcnt(0); // drain before overwriting Tr (q=1)
    }
}

// ---------------- 512x512 transpose (exact copy) ----------------
__global__ void transpose512(const float* __restrict__ in, float* __restrict__ out) {
    __shared__ float t[32][33];
    const int mat = blockIdx.z;
    const int bx = blockIdx.x * 32, by = blockIdx.y * 32;
    const int x = threadIdx.x & 31, yg = threadIdx.x >> 5;
    const float* I = in + (size_t)mat * N_SZ * K_SZ;
    float* O = out + (size_t)mat * N_SZ * K_SZ;
    #pragma unroll
    for (int i = 0; i < 4; ++i)
        t[yg * 4 + i][x] = I[(size_t)(by + yg * 4 + i) * 512 + bx + x];
    __syncthreads();
    #pragma unroll
    for (int i = 0; i < 4; ++i)
        O[(size_t)(bx + yg * 4 + i) * 512 + by + x] = t[x][yg * 4 + i];
}

__global__ void scale_kernel(float* __restrict__ p, float inv, int n4) {
    int i = blockIdx.x * blockDim.x + threadIdx.x;
    const int stride = gridDim.x * blockDim.x;
    for (; i < n4; i += stride) {
        float4 v = ((float4*)p)[i];
        v.x *= inv; v.y *= inv; v.z *= inv; v.w *= inv;
        ((float4*)p)[i] = v;
    }
}

extern "C" void kernel_launch(void* const* d_in, const int* in_sizes, int n_in,
                              void* d_out, int out_size, void* d_ws, size_t ws_size,
                              hipStream_t stream) {
    const float* x  = (const float*)d_in[0];   // [B, 512]
    const float* Wx = (const float*)d_in[1];   // [512, 512]
    const float* bx = (const float*)d_in[2];   // [512]
    const float* Ws = (const float*)d_in[3];   // [3, 512, 512]
    const float* bs = (const float*)d_in[4];   // [3, 512]
    // d_in[5] = time_step -> hardcoded 32

    const size_t BNt = (size_t)B_SZ * N_SZ;
    const size_t NK  = (size_t)N_SZ * K_SZ;

    float*    u   = (float*)d_ws;                 // [3][B][N] f32
    uint16_t* s   = (uint16_t*)(u + 3 * BNt);     // [3][B][N] bf16
    float*    x1  = (float*)(s + 3 * BNt);        // [B][N] f32
    float*    WxT = x1 + BNt;                     // [512][512]
    float*    WsT = WxT + NK;                     // [3][512][512]

    float*    a0 = (float*)d_out;
    float*    a2 = a0 + BNt;

    float*    u0 = u;       float*    u1 = u + BNt;   float*    u2 = u + 2 * BNt;
    uint16_t* s0 = s;       uint16_t* s1 = s + BNt;   uint16_t* s2 = s + 2 * BNt;

    dim3 blk(256);
    dim3 gridG(N_SZ / BN, B_SZ / BM);   // (4, 256)
    dim3 gridT1(16, 16, 1), gridT3(16, 16, 3);

    // ---- prep: transpose weights (exact copies) ----
    transpose512<<<gridT1, blk, 0, stream>>>(Wx, WxT);
    transpose512<<<gridT3, blk, 0, stream>>>(Ws, WsT);

    // ---- t = 0 ----
    vgemm_lif<false, 1, false, false, true><<<gridG, blk, 0, stream>>>(
        x, WxT, bx, nullptr, nullptr, u0, s0, a0, x1);
    vgemm_lif<true, 0, false, false, false><<<gridG, blk, 0, stream>>>(
        s0, WsT, bs, nullptr, nullptr, u1, s1, nullptr, nullptr);
    vgemm_lif<true, 1, false, false, false><<<gridG, blk, 0, stream>>>(
        s1, WsT + NK, bs + N_SZ, nullptr, nullptr, u2, s2, a2, nullptr);

    // ---- t = 1 .. T-1 ----
    for (int t = 1; t < T_STEPS; ++t) {
        vgemm_lif<true, 2, true, true, false><<<gridG, blk, 0, stream>>>(
            s2, WsT + 2 * NK, bs + 2 * N_SZ, u0, x1, u0, s0, a0, nullptr);
        vgemm_lif<true, 0, true, false, false><<<gridG, blk, 0, stream>>>(
            s0, WsT, bs, u1, nullptr, u1, s1, nullptr, nullptr);
        vgemm_lif<true, 2, true, false, false><<<gridG, blk, 0, stream>>>(
            s1, WsT + NK, bs + N_SZ, u2, nullptr, u2, s2, a2, nullptr);
    }

    // ---- finalize: a /= (1 - 0.9^32)/0.1 ----
    double p = 1.0;
    for (int i = 0; i < T_STEPS; ++i) p *= 0.9;
    const float inv = (float)(1.0 / ((1.0 - p) / 0.1));
    scale_kernel<<<2048, blk, 0, stream>>>((float*)d_out, inv, (int)(2 * BNt / 4));
}

// Round 5
// 11200.912 us; speedup vs baseline: 4.6915x; 4.6915x over previous
//
#include <hip/hip_runtime.h>
#include <stdint.h>

// SNN LIF multi-layer, B=16384, D_IN=N=512, L=3, T=32 (T hardcoded).
//
// Round 5: bitmask-driven row-GEMM.
//  - spikes are {0,1}: fmaf(s,w,acc) realization kept bit-identical to the
//    round-1/round-4 PASS (k ascending, single acc, fmaf) but s delivered as
//    SGPR bitmask bits -> s_cselect 1.0/0.0 -> v_fmac SGPR operand
//  - lane = 8-column stripe, wave = 8 batch rows, acc 8x8 in VGPRs
//  - W.T rows stream as coalesced per-lane dwordx4 (L1/L2 resident),
//    depth-2 prefetch, zero per-k address arithmetic
//  - ZERO LDS in the hot kernel; epilogue naturally coalesced
//  - producer epilogues emit the next layer's bitmask via __ballot
//  - gemm0 (continuous f32 x) = round-1's proven vector kernel

#define B_SZ 16384
#define N_SZ 512
#define K_SZ 512
#define T_STEPS 32
#define LEAKY 0.9f

// ---------------------------------------------------------------------------
// mask word assembly: lane c (0..15) builds the u32 covering cols 32c..32c+31
// of one row, from 8 ballots (ballot_j bit L = predicate of col 8L+j).
// bit t of word = ballot_{t&7} bit (4c + (t>>3)).
__device__ inline uint32_t mask_word(const unsigned long long bal[8], int lane) {
    const uint32_t sh = (4u * (uint32_t)lane) & 31u;
    uint32_t word = 0;
    #pragma unroll
    for (int j = 0; j < 8; ++j) {
        const uint32_t half = (lane < 8) ? (uint32_t)bal[j] : (uint32_t)(bal[j] >> 32);
        const uint32_t nib  = (half >> sh) & 0xFu;
        word |= ((nib * 0x00204081u) & 0x01010101u) << j;   // bits -> 0,8,16,24
    }
    return word;
}

// ---------------------------------------------------------------------------
// bitmask-driven GEMM + fused LIF.
// C[b,n] = chain_{k asc} fmaf(s_bk, Wt[k][n], acc) ; s from maskT_in.
// AMODE: 0 = none, 1 = a := s, 2 = a := a*LEAKY + s
template<int AMODE, bool ADD_U, bool ADD_X1>
__global__ __launch_bounds__(256, 2)
void rowgemm_lif(const uint32_t* __restrict__ mIn,  // [16][B] input spike bits
                 const float* __restrict__ Wt,      // [512 k][512 n] = W.T
                 const float* __restrict__ bias,    // [512]
                 const float* u_prev,               // may alias u_out
                 const float* __restrict__ x1,
                 float* u_out,
                 uint32_t* __restrict__ mOut,       // [16][B] output spike bits
                 float* a_ptr)
{
    const int lane = threadIdx.x & 63;
    const int w    = threadIdx.x >> 6;
    const int r0   = blockIdx.x * 32 + w * 8;     // 8 rows per wave
    const int cb   = lane * 8;                    // column stripe base

    float acc[8][8];
    #pragma unroll
    for (int m = 0; m < 8; ++m)
        #pragma unroll
        for (int j = 0; j < 8; ++j) acc[m][j] = 0.f;

    const float* wbase = Wt + cb;
    float4 w0a = ((const float4*)wbase)[0];
    float4 w0b = ((const float4*)wbase)[1];
    float4 w1a = ((const float4*)(wbase + K_SZ))[0];
    float4 w1b = ((const float4*)(wbase + K_SZ))[1];
    const float* wpf = wbase + 2 * K_SZ;          // next prefetch target (k+2)

    for (int c = 0; c < 16; ++c) {
        // 8 rows' mask words for this 32-k chunk (wave-uniform)
        uint32_t mw[8];
        {
            const uint32_t* mp = mIn + (size_t)c * B_SZ + r0;
            #pragma unroll
            for (int m = 0; m < 8; ++m)
                mw[m] = __builtin_amdgcn_readfirstlane(mp[m]);
        }
        #pragma unroll 8
        for (int kk2 = 0; kk2 < 16; ++kk2) {
            const int bit0 = 2 * kk2;
            // prefetch k+2, k+3
            const float4 n0a = ((const float4*)wpf)[0];
            const float4 n0b = ((const float4*)wpf)[1];
            const float4 n1a = ((const float4*)(wpf + K_SZ))[0];
            const float4 n1b = ((const float4*)(wpf + K_SZ))[1];
            wpf += 2 * K_SZ;
            // even k
            #pragma unroll
            for (int m = 0; m < 8; ++m) {
                const float sm = ((mw[m] >> bit0) & 1u) ? 1.0f : 0.0f;
                acc[m][0] = fmaf(sm, w0a.x, acc[m][0]);
                acc[m][1] = fmaf(sm, w0a.y, acc[m][1]);
                acc[m][2] = fmaf(sm, w0a.z, acc[m][2]);
                acc[m][3] = fmaf(sm, w0a.w, acc[m][3]);
                acc[m][4] = fmaf(sm, w0b.x, acc[m][4]);
                acc[m][5] = fmaf(sm, w0b.y, acc[m][5]);
                acc[m][6] = fmaf(sm, w0b.z, acc[m][6]);
                acc[m][7] = fmaf(sm, w0b.w, acc[m][7]);
            }
            // odd k
            #pragma unroll
            for (int m = 0; m < 8; ++m) {
                const float sm = ((mw[m] >> (bit0 + 1)) & 1u) ? 1.0f : 0.0f;
                acc[m][0] = fmaf(sm, w1a.x, acc[m][0]);
                acc[m][1] = fmaf(sm, w1a.y, acc[m][1]);
                acc[m][2] = fmaf(sm, w1a.z, acc[m][2]);
                acc[m][3] = fmaf(sm, w1a.w, acc[m][3]);
                acc[m][4] = fmaf(sm, w1b.x, acc[m][4]);
                acc[m][5] = fmaf(sm, w1b.y, acc[m][5]);
                acc[m][6] = fmaf(sm, w1b.z, acc[m][6]);
                acc[m][7] = fmaf(sm, w1b.w, acc[m][7]);
            }
            w0a = n0a; w0b = n0b; w1a = n1a; w1b = n1b;
        }
    }

    // ---- fused LIF epilogue (naturally coalesced; round-1 op order) ----
    float4 bva = ((const float4*)(bias + cb))[0];
    float4 bvb = ((const float4*)(bias + cb))[1];
    float bv[8] = {bva.x, bva.y, bva.z, bva.w, bvb.x, bvb.y, bvb.z, bvb.w};

    uint32_t pk[8];
    #pragma unroll
    for (int m = 0; m < 8; ++m) {
        const size_t row = (size_t)(r0 + m) * N_SZ + cb;
        float v[8];
        #pragma unroll
        for (int j = 0; j < 8; ++j) v[j] = acc[m][j] + bv[j];
        if (ADD_U) {
            const float4 ua = ((const float4*)(u_prev + row))[0];
            const float4 ub = ((const float4*)(u_prev + row))[1];
            v[0] += ua.x; v[1] += ua.y; v[2] += ua.z; v[3] += ua.w;
            v[4] += ub.x; v[5] += ub.y; v[6] += ub.z; v[7] += ub.w;
        }
        if (ADD_X1) {
            const float4 xa = ((const float4*)(x1 + row))[0];
            const float4 xb = ((const float4*)(x1 + row))[1];
            v[0] += xa.x; v[1] += xa.y; v[2] += xa.z; v[3] += xa.w;
            v[4] += xb.x; v[5] += xb.y; v[6] += xb.z; v[7] += xb.w;
        }
        float un[8], sv[8];
        #pragma unroll
        for (int j = 0; j < 8; ++j) {
            sv[j] = (v[j] >= 1.0f) ? 1.0f : 0.0f;
            un[j] = (v[j] - 2.0f * sv[j]) * LEAKY;
        }
        ((float4*)(u_out + row))[0] = (float4){un[0], un[1], un[2], un[3]};
        ((float4*)(u_out + row))[1] = (float4){un[4], un[5], un[6], un[7]};
        if (AMODE == 1) {
            ((float4*)(a_ptr + row))[0] = (float4){sv[0], sv[1], sv[2], sv[3]};
            ((float4*)(a_ptr + row))[1] = (float4){sv[4], sv[5], sv[6], sv[7]};
        } else if (AMODE == 2) {
            const float4 aa = ((const float4*)(a_ptr + row))[0];
            const float4 ab = ((const float4*)(a_ptr + row))[1];
            ((float4*)(a_ptr + row))[0] = (float4){aa.x * LEAKY + sv[0], aa.y * LEAKY + sv[1],
                                                   aa.z * LEAKY + sv[2], aa.w * LEAKY + sv[3]};
            ((float4*)(a_ptr + row))[1] = (float4){ab.x * LEAKY + sv[4], ab.y * LEAKY + sv[5],
                                                   ab.z * LEAKY + sv[6], ab.w * LEAKY + sv[7]};
        }
        // spike bits -> ballots -> mask word
        unsigned long long bal[8];
        #pragma unroll
        for (int j = 0; j < 8; ++j) bal[j] = __ballot(v[j] >= 1.0f);
        pk[m] = mask_word(bal, lane);
    }
    if (lane < 16) {
        uint32_t* mp = mOut + (size_t)lane * B_SZ + r0;
        ((uint4*)mp)[0] = (uint4){pk[0], pk[1], pk[2], pk[3]};
        ((uint4*)mp)[1] = (uint4){pk[4], pk[5], pk[6], pk[7]};
    }
}

// ---------------------------------------------------------------------------
// bitmask from bf16 spikes (for s0 produced by gemm0)
__global__ void mask_build(const uint16_t* __restrict__ s, uint32_t* __restrict__ mOut) {
    const int lane = threadIdx.x & 63;
    const int w    = threadIdx.x >> 6;
    const int r0   = blockIdx.x * 32 + w * 8;
    const int cb   = lane * 8;
    uint32_t pk[8];
    #pragma unroll
    for (int m = 0; m < 8; ++m) {
        const ushort4 sa = ((const ushort4*)(s + (size_t)(r0 + m) * N_SZ + cb))[0];
        const ushort4 sb = ((const ushort4*)(s + (size_t)(r0 + m) * N_SZ + cb))[1];
        const uint16_t sv[8] = {sa.x, sa.y, sa.z, sa.w, sb.x, sb.y, sb.z, sb.w};
        unsigned long long bal[8];
        #pragma unroll
        for (int j = 0; j < 8; ++j) bal[j] = __ballot(sv[j] != 0);
        pk[m] = mask_word(bal, lane);
    }
    if (lane < 16) {
        uint32_t* mp = mOut + (size_t)lane * B_SZ + r0;
        ((uint4*)mp)[0] = (uint4){pk[0], pk[1], pk[2], pk[3]};
        ((uint4*)mp)[1] = (uint4){pk[4], pk[5], pk[6], pk[7]};
    }
}

// ---------------------------------------------------------------------------
// f32 vector GEMM for the first (continuous-x) GEMM — round-1 math verbatim.
#define BM 128
#define BN 128
#define BK 16
#define TM 8
#define TN 8
#define PAD 4

__global__ __launch_bounds__(256, 2)
void gemm0_lif(const float* __restrict__ A, const float* __restrict__ W,
               const float* __restrict__ bias, float* __restrict__ u_out,
               uint16_t* __restrict__ s_out, float* __restrict__ a_ptr,
               float* __restrict__ c_out) {
    __shared__ float As[BK][BM + PAD];
    __shared__ float Bs[BK][BN + PAD];
    const int tid = threadIdx.x;
    const int tx = tid & 15, ty = tid >> 4;
    const int m0 = blockIdx.y * BM, n0 = blockIdx.x * BN;
    float acc[TM][TN];
    #pragma unroll
    for (int i = 0; i < TM; ++i)
        #pragma unroll
        for (int j = 0; j < TN; ++j) acc[i][j] = 0.f;
    const int lr = tid >> 2, lc = (tid & 3) * 4;
    for (int k0 = 0; k0 < K_SZ; k0 += BK) {
        #pragma unroll
        for (int h = 0; h < 2; ++h) {
            const int r = lr + h * 64;
            const float4 v = *(const float4*)(A + (size_t)(m0 + r) * K_SZ + k0 + lc);
            As[lc + 0][r] = v.x; As[lc + 1][r] = v.y;
            As[lc + 2][r] = v.z; As[lc + 3][r] = v.w;
        }
        #pragma unroll
        for (int h = 0; h < 2; ++h) {
            const int r = lr + h * 64;
            const float4 v = *(const float4*)(W + (size_t)(n0 + r) * K_SZ + k0 + lc);
            Bs[lc + 0][r] = v.x; Bs[lc + 1][r] = v.y;
            Bs[lc + 2][r] = v.z; Bs[lc + 3][r] = v.w;
        }
        __syncthreads();
        #pragma unroll
        for (int kk = 0; kk < BK; ++kk) {
            float av[TM], bvv[TN];
            #pragma unroll
            for (int i = 0; i < TM; ++i) av[i] = As[kk][ty * TM + i];
            #pragma unroll
            for (int j = 0; j < TN; ++j) bvv[j] = Bs[kk][tx * TN + j];
            #pragma unroll
            for (int i = 0; i < TM; ++i)
                #pragma unroll
                for (int j = 0; j < TN; ++j)
                    acc[i][j] = fmaf(av[i], bvv[j], acc[i][j]);
        }
        __syncthreads();
    }
    #pragma unroll
    for (int i = 0; i < TM; ++i) {
        const size_t row = (size_t)(m0 + ty * TM + i) * N_SZ + n0 + tx * TN;
        #pragma unroll
        for (int j = 0; j < TN; ++j) {
            const float v = acc[i][j] + bias[n0 + tx * TN + j];
            c_out[row + j] = v;
            const float sv = (v >= 1.0f) ? 1.0f : 0.0f;
            u_out[row + j] = (v - 2.0f * sv) * LEAKY;
            s_out[row + j] = (v >= 1.0f) ? (uint16_t)0x3F80 : (uint16_t)0;
            a_ptr[row + j] = sv;
        }
    }
}

// ---------------- 512x512 transpose (exact copy) ----------------
__global__ void transpose512(const float* __restrict__ in, float* __restrict__ out) {
    __shared__ float t[32][33];
    const int mat = blockIdx.z;
    const int bx = blockIdx.x * 32, by = blockIdx.y * 32;
    const int x = threadIdx.x & 31, yg = threadIdx.x >> 5;
    const float* I = in + (size_t)mat * N_SZ * K_SZ;
    float* O = out + (size_t)mat * N_SZ * K_SZ;
    #pragma unroll
    for (int i = 0; i < 4; ++i)
        t[yg * 4 + i][x] = I[(size_t)(by + yg * 4 + i) * 512 + bx + x];
    __syncthreads();
    #pragma unroll
    for (int i = 0; i < 4; ++i)
        O[(size_t)(bx + yg * 4 + i) * 512 + by + x] = t[x][yg * 4 + i];
}

__global__ void scale_kernel(float* __restrict__ p, float inv, int n4) {
    int i = blockIdx.x * blockDim.x + threadIdx.x;
    const int stride = gridDim.x * blockDim.x;
    for (; i < n4; i += stride) {
        float4 v = ((float4*)p)[i];
        v.x *= inv; v.y *= inv; v.z *= inv; v.w *= inv;
        ((float4*)p)[i] = v;
    }
}

extern "C" void kernel_launch(void* const* d_in, const int* in_sizes, int n_in,
                              void* d_out, int out_size, void* d_ws, size_t ws_size,
                              hipStream_t stream) {
    const float* x  = (const float*)d_in[0];
    const float* Wx = (const float*)d_in[1];
    const float* bx = (const float*)d_in[2];
    const float* Ws = (const float*)d_in[3];
    const float* bs = (const float*)d_in[4];
    // d_in[5] = time_step -> hardcoded 32

    const size_t BNt = (size_t)B_SZ * N_SZ;
    const size_t NK  = (size_t)N_SZ * K_SZ;
    const size_t MSZ = (size_t)16 * B_SZ;          // mask words per layer

    float*    u   = (float*)d_ws;                  // [3][B][N] f32   (96 MB)
    float*    x1  = u + 3 * BNt;                   // [B][N] f32      (32 MB)
    uint16_t* s0b = (uint16_t*)(x1 + BNt);         // [B][N] bf16     (16 MB)
    float*    WsT = (float*)(s0b + BNt);           // [3][512][512]   (3 MB)
    uint32_t* mT  = (uint32_t*)(WsT + 3 * NK + 1024); // 4KB prefetch slack
    uint32_t* mT0 = mT;
    uint32_t* mT1 = mT + MSZ;
    uint32_t* mT2 = mT + 2 * MSZ;

    float* a0 = (float*)d_out;
    float* a2 = a0 + BNt;
    float* u0 = u; float* u1 = u + BNt; float* u2 = u + 2 * BNt;

    dim3 blk(256);
    dim3 gridV(N_SZ / BN, B_SZ / BM);   // gemm0: (4, 128)
    dim3 gridR(B_SZ / 32);              // rowgemm/mask_build: 512
    dim3 gridT(16, 16, 3);

    // ---- prep ----
    transpose512<<<gridT, blk, 0, stream>>>(Ws, WsT);

    // ---- t = 0 ----
    gemm0_lif<<<gridV, blk, 0, stream>>>(x, Wx, bx, u0, s0b, a0, x1);
    mask_build<<<gridR, blk, 0, stream>>>(s0b, mT0);
    rowgemm_lif<0, false, false><<<gridR, blk, 0, stream>>>(
        mT0, WsT, bs, nullptr, nullptr, u1, mT1, nullptr);
    rowgemm_lif<1, false, false><<<gridR, blk, 0, stream>>>(
        mT1, WsT + NK, bs + N_SZ, nullptr, nullptr, u2, mT2, a2);

    // ---- t = 1 .. T-1 ----
    for (int t = 1; t < T_STEPS; ++t) {
        rowgemm_lif<2, true, true><<<gridR, blk, 0, stream>>>(
            mT2, WsT + 2 * NK, bs + 2 * N_SZ, u0, x1, u0, mT0, a0);
        rowgemm_lif<0, true, false><<<gridR, blk, 0, stream>>>(
            mT0, WsT, bs, u1, nullptr, u1, mT1, nullptr);
        rowgemm_lif<2, true, false><<<gridR, blk, 0, stream>>>(
            mT1, WsT + NK, bs + N_SZ, u2, nullptr, u2, mT2, a2);
    }

    // ---- finalize: a /= (1 - 0.9^32)/0.1 ----
    double p = 1.0;
    for (int i = 0; i < T_STEPS; ++i) p *= 0.9;
    const float inv = (float)(1.0 / ((1.0 - p) / 0.1));
    scale_kernel<<<2048, blk, 0, stream>>>((float*)d_out, inv, (int)(2 * BNt / 4));
}